// Round 1
// baseline (879.481 us; speedup 1.0000x reference)
//
#include <hip/hip_runtime.h>

namespace {
constexpr int BATCH = 8;
constexpr int WIDTH = 48;
constexpr int N = WIDTH * WIDTH;   // 2304
constexpr int PW = 55;             // padded row stride: 48 + 6 halo + 1 bank pad
constexpr int PH = 54;             // 48 + 6 halo
constexpr int NT = 768;            // 12 waves; each thread owns 3 adjacent pixels
constexpr int NWAVE = NT / 64;
constexpr float EPS = 1e-8f;
constexpr int MAX_ITERS = 250;
constexpr float TOLSQ = 1e-10f;    // (1e-5)^2
}

__device__ __forceinline__ float wave_sum(float v) {
#pragma unroll
  for (int off = 32; off > 0; off >>= 1) v += __shfl_down(v, off);
  return v;
}

// Block-wide sum, result uniform across all threads (everyone sums the same
// 12 partials in the same order -> bitwise-identical -> uniform branches OK).
__device__ __forceinline__ float block_sum(float v, float* buf, int tid) {
  v = wave_sum(v);
  if ((tid & 63) == 0) buf[tid >> 6] = v;
  __syncthreads();
  float t = 0.f;
#pragma unroll
  for (int w = 0; w < NWAVE; ++w) t += buf[w];
  __syncthreads();  // allow buf reuse
  return t;
}

__device__ __forceinline__ float2 block_sum2(float a, float b, float* buf, int tid) {
  a = wave_sum(a);
  b = wave_sum(b);
  if ((tid & 63) == 0) { buf[tid >> 6] = a; buf[16 + (tid >> 6)] = b; }
  __syncthreads();
  float ta = 0.f, tb = 0.f;
#pragma unroll
  for (int w = 0; w < NWAVE; ++w) { ta += buf[w]; tb += buf[16 + w]; }
  __syncthreads();
  return make_float2(ta, tb);
}

// 25-tap diamond (L1 radius 3) conv on the padded LDS grid; 3 adjacent outputs
// per thread so horizontal taps are shared (compiler CSEs overlapping ds_reads).
// SEL=0: weights (exp(-5d) - eps)      [K local part]
// SEL=1: weights d*(exp(-5d) - eps)    [K*cost local part; d=0 tap is zero]
template <int SEL>
__device__ __forceinline__ void conv25(const float* __restrict__ pad, int ip, float o[3]) {
  float a0 = 0.f, a1 = 0.f, a2 = 0.f;
#pragma unroll
  for (int dr = -3; dr <= 3; ++dr) {
    const int adr = dr < 0 ? -dr : dr;
    const int wd = 3 - adr;
    const float* rp = pad + ip + dr * PW;
#pragma unroll
    for (int dc = -wd; dc <= wd; ++dc) {
      const int adc = dc < 0 ? -dc : dc;
      const int d = adr + adc;
      float wgt;
      if (SEL == 0) {
        wgt = (d == 0) ? 1.0f            // 1 - 1e-8 rounds to 1.0f
            : (d == 1) ? 6.7379370e-3f   // exp(-5)  - 1e-8
            : (d == 2) ? 4.5389930e-5f   // exp(-10) - 1e-8
                       : 2.9590232e-7f;  // exp(-15) - 1e-8
      } else {
        if (d == 0) continue;
        wgt = (d == 1) ? 6.7379370e-3f   // 1*(exp(-5)  - 1e-8)
            : (d == 2) ? 9.0779860e-5f   // 2*(exp(-10) - 1e-8)
                       : 8.8770696e-7f;  // 3*(exp(-15) - 1e-8)
      }
      a0 += wgt * rp[dc];
      a1 += wgt * rp[dc + 1];
      a2 += wgt * rp[dc + 2];
    }
  }
  o[0] = a0; o[1] = a1; o[2] = a2;
}

__global__ __launch_bounds__(NT, 1) void sinkhorn48(const float* __restrict__ x,
                                                    const float* __restrict__ y,
                                                    float* __restrict__ out) {
  __shared__ float xs[N];
  __shared__ float ys[N];
  __shared__ float upad[PH * PW];
  __shared__ float vpad[PH * PW];
  __shared__ float red[32];
  __shared__ float vr[WIDTH];
  __shared__ float vc[WIDTH];

  const int tid = threadIdx.x;
  const int b = blockIdx.x;
  const int row = tid >> 4;           // 48 rows, 16 threads per row
  const int c0 = (tid & 15) * 3;      // 3 adjacent columns per thread
  const int p0 = row * WIDTH + c0;
  const int ip = (row + 3) * PW + (c0 + 3);

  // Zero halos (and interiors) of the padded grids.
  for (int i = tid; i < PH * PW; i += NT) { upad[i] = 0.f; vpad[i] = 0.f; }

  // Load this batch's images, normalize to probability vectors in LDS.
  const float* xb = x + b * N;
  const float* yb = y + b * N;
  const float rx0 = xb[p0], rx1 = xb[p0 + 1], rx2 = xb[p0 + 2];
  const float ry0 = yb[p0], ry1 = yb[p0 + 1], ry2 = yb[p0 + 2];
  const float2 sxy = block_sum2(rx0 + rx1 + rx2, ry0 + ry1 + ry2, red, tid);
  // (barrier inside block_sum2 also separates the zero-init from interior fills)
  xs[p0] = rx0 / sxy.x; xs[p0 + 1] = rx1 / sxy.x; xs[p0 + 2] = rx2 / sxy.x;
  ys[p0] = ry0 / sxy.y; ys[p0 + 1] = ry1 / sxy.y; ys[p0 + 2] = ry2 / sxy.y;

  const float u0 = 1.0f / (float)N;
  upad[ip] = u0; upad[ip + 1] = u0; upad[ip + 2] = u0;

  float Su = block_sum(3.0f * u0, red, tid);  // publishes xs/ys/upad too

  float a[3];
  for (int iter = 0; iter < MAX_ITERS; ++iter) {
    // v = ys / (u @ K);  (u@K)_j = eps*sum(u) + local conv
    conv25<0>(upad, ip, a);
    float base = EPS * Su;
    const float v0 = ys[p0] / (base + a[0]);
    const float v1 = ys[p0 + 1] / (base + a[1]);
    const float v2 = ys[p0 + 2] / (base + a[2]);
    vpad[ip] = v0; vpad[ip + 1] = v1; vpad[ip + 2] = v2;
    const float Sv = block_sum(v0 + v1 + v2, red, tid);  // barrier publishes vpad

    // u_new = xs / (v @ K)
    conv25<0>(vpad, ip, a);
    base = EPS * Sv;
    const float un0 = xs[p0] / (base + a[0]);
    const float un1 = xs[p0 + 1] / (base + a[1]);
    const float un2 = xs[p0 + 2] / (base + a[2]);
    const float d0 = upad[ip] - un0;
    const float d1 = upad[ip + 1] - un1;
    const float d2 = upad[ip + 2] - un2;
    upad[ip] = un0; upad[ip + 1] = un1; upad[ip + 2] = un2;
    const float2 r =
        block_sum2(un0 + un1 + un2, d0 * d0 + d1 * d1 + d2 * d2, red, tid);
    Su = r.x;
    // Reference freezes u once done -> all later iterations are no-ops, so a
    // uniform break at the identical condition is exactly equivalent.
    if (iter > 0 && r.y < TOLSQ) break;
  }

  // Final v from converged u.
  conv25<0>(upad, ip, a);
  const float base = EPS * Su;
  const float v0 = ys[p0] / (base + a[0]);
  const float v1 = ys[p0 + 1] / (base + a[1]);
  const float v2 = ys[p0 + 2] / (base + a[2]);
  vpad[ip] = v0; vpad[ip + 1] = v1; vpad[ip + 2] = v2;
  __syncthreads();

  // Row/col marginals of v for the separable eps*(C @ v) term.
  if (tid < WIDTH) {
    float s = 0.f;
    const float* rp = vpad + (tid + 3) * PW + 3;
    for (int c = 0; c < WIDTH; ++c) s += rp[c];
    vr[tid] = s;
  } else if (tid >= 64 && tid < 64 + WIDTH) {
    const int c = tid - 64;
    float s = 0.f;
    const float* cp = vpad + 3 * PW + 3 + c;
    for (int r = 0; r < WIDTH; ++r) s += cp[r * PW];
    vc[c] = s;
  }
  __syncthreads();

  // dist_b = sum_j u_j * ((K*C) @ v)_j
  //        = sum_j u_j * ( eps*(Cv)_j + local distance-weighted conv )
  float aD[3];
  conv25<1>(vpad, ip, aD);
  float cvr = 0.f;
  for (int r = 0; r < WIDTH; ++r) cvr += vr[r] * fabsf((float)(r - row));
  float part = 0.f;
#pragma unroll
  for (int k = 0; k < 3; ++k) {
    const int cc = c0 + k;
    float cvc = 0.f;
    for (int c = 0; c < WIDTH; ++c) cvc += vc[c] * fabsf((float)(c - cc));
    const float t = EPS * (cvr + cvc) + aD[k];
    part += upad[ip + k] * t;
  }
  const float dist = block_sum(part, red, tid);
  if (tid == 0) out[b] = dist;
}

extern "C" void kernel_launch(void* const* d_in, const int* in_sizes, int n_in,
                              void* d_out, int out_size, void* d_ws, size_t ws_size,
                              hipStream_t stream) {
  const float* x = (const float*)d_in[0];
  const float* y = (const float*)d_in[1];
  float* out = (float*)d_out;
  sinkhorn48<<<BATCH, NT, 0, stream>>>(x, y, out);
}

// Round 2
// 666.631 us; speedup vs baseline: 1.3193x; 1.3193x over previous
//
#include <hip/hip_runtime.h>

namespace {
constexpr int BATCH = 8;
constexpr int WIDTH = 48;
constexpr int N = WIDTH * WIDTH;   // 2304
// PW=56: 56 mod 32 = 24 -> the 4 rows of a wave sit at bank offsets {0,24,16,8}.
// Combined with the 16-lane column set {3k mod 32} (which covers exactly one of
// each {b,b+16} pair) every conv read/write is a uniform 2-way pattern = free.
constexpr int PW = 56;
constexpr int PH = 54;             // 48 + 6 halo
constexpr int NT = 768;            // 12 waves, 3 waves/SIMD; thread owns 3 adjacent pixels
constexpr int NWAVE = NT / 64;
constexpr float EPS = 1e-8f;
constexpr int MAX_ITERS = 250;
constexpr float TOLSQ = 1e-10f;    // (1e-5)^2
}

__device__ __forceinline__ float wave_sum(float v) {
#pragma unroll
  for (int off = 32; off > 0; off >>= 1) v += __shfl_down(v, off);
  return v;
}

__device__ __forceinline__ float sum12(const float* buf) {
  // buf is 16B-aligned; 3x ds_read_b128, broadcast (all lanes same addr) = conflict-free
  const float4* b4 = (const float4*)buf;
  float4 a = b4[0], b = b4[1], c = b4[2];
  return ((a.x + a.y) + (a.z + a.w)) + ((b.x + b.y) + (b.z + b.w)) +
         ((c.x + c.y) + (c.z + c.w));
}

// 25-tap diamond (L1 radius 3) conv on the padded LDS grid; 3 adjacent outputs
// per thread. Thread's own 3 center values come in as registers (o0..o2) so the
// dr==0, j in [0,3) taps need no LDS read.
// SEL=0: weights (exp(-5d) - eps)      [K local part]
// SEL=1: weights d*(exp(-5d) - eps)    [K*cost local part; d=0 tap is zero]
template <int SEL>
__device__ __forceinline__ void conv25(const float* __restrict__ pad, int ip,
                                       float o0, float o1, float o2, float out[3]) {
  float a0 = 0.f, a1 = 0.f, a2 = 0.f;
#pragma unroll
  for (int dr = -3; dr <= 3; ++dr) {
    const int adr = dr < 0 ? -dr : dr;
    const int wd = 3 - adr;
    const float* rp = pad + ip + dr * PW;
    float rowv[9];
#pragma unroll
    for (int j = -wd; j <= wd + 2; ++j) {
      if (dr == 0 && j >= 0 && j < 3)
        rowv[j + 3] = (j == 0) ? o0 : ((j == 1) ? o1 : o2);
      else
        rowv[j + 3] = rp[j];
    }
#pragma unroll
    for (int dc = -wd; dc <= wd; ++dc) {
      const int d = adr + (dc < 0 ? -dc : dc);
      float wgt;
      if (SEL == 0) {
        wgt = (d == 0) ? 1.0f            // 1 - 1e-8 rounds to 1.0f
            : (d == 1) ? 6.7379370e-3f   // exp(-5)  - 1e-8
            : (d == 2) ? 4.5389930e-5f   // exp(-10) - 1e-8
                       : 2.9590232e-7f;  // exp(-15) - 1e-8
      } else {
        if (d == 0) continue;
        wgt = (d == 1) ? 6.7379370e-3f
            : (d == 2) ? 9.0779860e-5f   // 2*(exp(-10) - 1e-8)
                       : 8.8770696e-7f;  // 3*(exp(-15) - 1e-8)
      }
      a0 += wgt * rowv[dc + 3];
      a1 += wgt * rowv[dc + 4];
      a2 += wgt * rowv[dc + 5];
    }
  }
  out[0] = a0; out[1] = a1; out[2] = a2;
}

__global__ __launch_bounds__(NT, 1) void sinkhorn48(const float* __restrict__ x,
                                                    const float* __restrict__ y,
                                                    float* __restrict__ out) {
  __shared__ float upad[PH * PW];
  __shared__ float vpad[PH * PW];
  __shared__ alignas(16) float rA[16];  // Su partials (loop) / x-sum (init) / dist partials
  __shared__ alignas(16) float rB[16];  // Sv partials (loop) / y-sum (init)
  __shared__ alignas(16) float rC[16];  // diff^2 partials
  __shared__ float vr[WIDTH];
  __shared__ float vc[WIDTH];

  const int tid = threadIdx.x;
  const int b = blockIdx.x;
  const int row = tid >> 4;           // 48 rows, 16 threads per row
  const int c0 = (tid & 15) * 3;      // 3 adjacent columns per thread
  const int p0 = row * WIDTH + c0;
  const int ip = (row + 3) * PW + (c0 + 3);
  const int wid = tid >> 6;
  const int lane = tid & 63;

  // Zero halos (and interiors) of the padded grids.
  for (int i = tid; i < PH * PW; i += NT) { upad[i] = 0.f; vpad[i] = 0.f; }

  // Load this batch's pixels into registers; block-sum for normalization.
  const float* xb = x + b * N;
  const float* yb = y + b * N;
  const float rx0 = xb[p0], rx1 = xb[p0 + 1], rx2 = xb[p0 + 2];
  const float ry0 = yb[p0], ry1 = yb[p0 + 1], ry2 = yb[p0 + 2];
  {
    const float px = wave_sum(rx0 + rx1 + rx2);
    const float py = wave_sum(ry0 + ry1 + ry2);
    if (lane == 0) { rA[wid] = px; rB[wid] = py; }
  }
  __syncthreads();  // B0: publishes rA/rB partials, zeroed pads
  const float irx = __builtin_amdgcn_rcpf(sum12(rA));
  const float iry = __builtin_amdgcn_rcpf(sum12(rB));
  const float xr0 = rx0 * irx, xr1 = rx1 * irx, xr2 = rx2 * irx;
  const float yr0 = ry0 * iry, yr1 = ry1 * iry, yr2 = ry2 * iry;

  float ur0 = 1.0f / (float)N, ur1 = ur0, ur2 = ur0;
  upad[ip] = ur0; upad[ip + 1] = ur1; upad[ip + 2] = ur2;
  __syncthreads();  // B1: separates rA/rB reads above from rewrite below
  if (tid < NWAVE) { rA[tid] = 1.0f / (float)NWAVE; rC[tid] = 1.0f; }
  __syncthreads();  // B2: publishes rA (Su(u0)=1), rC dummy, upad interior

  float cc[3];
  for (int iter = 0; iter < MAX_ITERS; ++iter) {
    // Sums of partials published at last barrier; reads are independent of the
    // conv below, so their latency hides behind it.
    const float Su = sum12(rA);
    const float dsq = sum12(rC);
    conv25<0>(upad, ip, ur0, ur1, ur2, cc);
    // Reference: u_next = u_new at the first iter (i>0) with diff<TOL, then
    // frozen. dsq here is from iteration (iter-1), i.e. ref index i=iter-1;
    // break before any state write -> upad == that u_new. Exact.
    if (iter >= 2 && dsq < TOLSQ) break;
    float base = EPS * Su;
    const float v0 = yr0 * __builtin_amdgcn_rcpf(base + cc[0]);
    const float v1 = yr1 * __builtin_amdgcn_rcpf(base + cc[1]);
    const float v2 = yr2 * __builtin_amdgcn_rcpf(base + cc[2]);
    vpad[ip] = v0; vpad[ip + 1] = v1; vpad[ip + 2] = v2;
    {
      const float pv = wave_sum(v0 + v1 + v2);
      if (lane == 0) rB[wid] = pv;
    }
    __syncthreads();  // A: publishes vpad + Sv partials

    const float Sv = sum12(rB);  // hides behind conv(vpad)
    conv25<0>(vpad, ip, v0, v1, v2, cc);
    base = EPS * Sv;
    const float un0 = xr0 * __builtin_amdgcn_rcpf(base + cc[0]);
    const float un1 = xr1 * __builtin_amdgcn_rcpf(base + cc[1]);
    const float un2 = xr2 * __builtin_amdgcn_rcpf(base + cc[2]);
    const float d0 = ur0 - un0, d1 = ur1 - un1, d2 = ur2 - un2;
    ur0 = un0; ur1 = un1; ur2 = un2;
    upad[ip] = un0; upad[ip + 1] = un1; upad[ip + 2] = un2;
    {
      const float psu = wave_sum(un0 + un1 + un2);
      const float pd = wave_sum(d0 * d0 + d1 * d1 + d2 * d2);
      if (lane == 0) { rA[wid] = psu; rC[wid] = pd; }
    }
    __syncthreads();  // B: publishes upad + Su/diff partials
  }

  // Final v from converged u. rA partials match current upad on both exit paths.
  const float SuF = sum12(rA);
  conv25<0>(upad, ip, ur0, ur1, ur2, cc);
  const float base = EPS * SuF;
  const float v0 = yr0 * __builtin_amdgcn_rcpf(base + cc[0]);
  const float v1 = yr1 * __builtin_amdgcn_rcpf(base + cc[1]);
  const float v2 = yr2 * __builtin_amdgcn_rcpf(base + cc[2]);
  vpad[ip] = v0; vpad[ip + 1] = v1; vpad[ip + 2] = v2;
  __syncthreads();

  // Row/col marginals of v for the separable eps*(C @ v) term.
  if (tid < WIDTH) {
    float s = 0.f;
    const float* rp = vpad + (tid + 3) * PW + 3;
    for (int c = 0; c < WIDTH; ++c) s += rp[c];
    vr[tid] = s;
  } else if (tid >= 64 && tid < 64 + WIDTH) {
    const int c = tid - 64;
    float s = 0.f;
    const float* cp = vpad + 3 * PW + 3 + c;
    for (int r = 0; r < WIDTH; ++r) s += cp[r * PW];
    vc[c] = s;
  }
  __syncthreads();

  // dist_b = sum_j u_j * ( eps*(Cv)_j + distance-weighted local conv )
  float aD[3];
  conv25<1>(vpad, ip, v0, v1, v2, aD);
  float cvr = 0.f;
  for (int r = 0; r < WIDTH; ++r) cvr += vr[r] * fabsf((float)(r - row));
  float part = 0.f;
#pragma unroll
  for (int k = 0; k < 3; ++k) {
    const int ccol = c0 + k;
    float cvc = 0.f;
    for (int c = 0; c < WIDTH; ++c) cvc += vc[c] * fabsf((float)(c - ccol));
    const float uk = (k == 0) ? ur0 : (k == 1) ? ur1 : ur2;
    part += uk * (EPS * (cvr + cvc) + aD[k]);
  }
  {
    const float p = wave_sum(part);
    if (lane == 0) rA[wid] = p;  // WAR on rA separated by the two barriers above
  }
  __syncthreads();
  if (tid == 0) out[b] = sum12(rA);
}

extern "C" void kernel_launch(void* const* d_in, const int* in_sizes, int n_in,
                              void* d_out, int out_size, void* d_ws, size_t ws_size,
                              hipStream_t stream) {
  const float* x = (const float*)d_in[0];
  const float* y = (const float*)d_in[1];
  float* out = (float*)d_out;
  sinkhorn48<<<BATCH, NT, 0, stream>>>(x, y, out);
}

// Round 3
// 561.728 us; speedup vs baseline: 1.5657x; 1.1867x over previous
//
#include <hip/hip_runtime.h>

namespace {
constexpr int BATCH = 8;
constexpr int WIDTH = 48;
constexpr int N = WIDTH * WIDTH;   // 2304
// PW=56: row stride mod 32 = 24; tile-row stride 3*56 mod 32 = 8. A wave's 4
// tile-row groups sit at bank offsets {0,8,16,24}; the 16-lane column set
// {3k mod 32} covers exactly one of each {b, b+16} bank pair, so every conv
// read/write is a uniform 2-lanes-per-bank pattern (free on CDNA4).
constexpr int PW = 56;
constexpr int PH = 54;             // 48 + 6 halo
constexpr int NT = 256;            // 4 waves; each thread owns a 3x3 pixel tile
constexpr int NWAVE = NT / 64;
constexpr float EPS = 1e-8f;
constexpr int MAX_ITERS = 250;
constexpr float TOLSQ = 1e-10f;    // (1e-5)^2
}

__device__ __forceinline__ float wave_sum(float v) {
#pragma unroll
  for (int off = 32; off > 0; off >>= 1) v += __shfl_down(v, off);
  return v;
}

__device__ __forceinline__ float sum4(const float* buf) {
  const float4 a = *(const float4*)buf;  // broadcast b128, conflict-free
  return (a.x + a.y) + (a.z + a.w);
}

// Diamond (L1 radius 3) conv producing a 3x3 output tile. The thread's own 9
// center values arrive in registers (c[]) so the 9 interior taps need no LDS
// read: 48 ds_reads per 9 outputs. Fully unrolled: 225 FMAs (SEL=0).
// SEL=0: weights (exp(-5d) - eps)      [K local part]
// SEL=1: weights d*(exp(-5d) - eps)    [K*cost local part; d=0 tap is zero]
template <int SEL>
__device__ __forceinline__ void conv_tile(const float* __restrict__ pad, int ip,
                                          const float* __restrict__ c,
                                          float* __restrict__ out) {
  float acc[9];
#pragma unroll
  for (int i = 0; i < 9; ++i) acc[i] = 0.f;
#pragma unroll
  for (int rho = -3; rho <= 5; ++rho) {   // input row relative to tile row 0
    const int drmin = (rho < 0) ? -rho : (rho > 2 ? rho - 2 : 0);
    const int w = 3 - drmin;              // widest halo any output row needs
    float rowv[9];
    const float* rp = pad + ip + rho * PW;
#pragma unroll
    for (int m = -w; m <= 2 + w; ++m) {
      if (rho >= 0 && rho <= 2 && m >= 0 && m <= 2)
        rowv[m + 3] = c[rho * 3 + m];
      else
        rowv[m + 3] = rp[m];
    }
#pragma unroll
    for (int r = 0; r < 3; ++r) {
      int d = rho - r; d = d < 0 ? -d : d;
      if (d > 3) continue;
#pragma unroll
      for (int k = 0; k < 3; ++k) {
#pragma unroll
        for (int m = -3; m <= 3; ++m) {
          if (m < -(3 - d) || m > (3 - d)) continue;
          const int dist = d + (m < 0 ? -m : m);
          float wgt;
          if (SEL == 0) {
            wgt = (dist == 0) ? 1.0f            // 1 - 1e-8 rounds to 1.0f
                : (dist == 1) ? 6.7379370e-3f   // exp(-5)  - 1e-8
                : (dist == 2) ? 4.5389930e-5f   // exp(-10) - 1e-8
                              : 2.9590232e-7f;  // exp(-15) - 1e-8
          } else {
            if (dist == 0) continue;
            wgt = (dist == 1) ? 6.7379370e-3f
                : (dist == 2) ? 9.0779860e-5f   // 2*(exp(-10) - 1e-8)
                              : 8.8770696e-7f;  // 3*(exp(-15) - 1e-8)
          }
          acc[r * 3 + k] += wgt * rowv[k + m + 3];
        }
      }
    }
  }
#pragma unroll
  for (int i = 0; i < 9; ++i) out[i] = acc[i];
}

__global__ __launch_bounds__(NT, 1) void sinkhorn48(const float* __restrict__ x,
                                                    const float* __restrict__ y,
                                                    float* __restrict__ out) {
  __shared__ float upad[PH * PW];
  __shared__ float vpad[PH * PW];
  __shared__ alignas(16) float rA[4];  // Su partials / x-sum / dist partials
  __shared__ alignas(16) float rB[4];  // Sv partials / y-sum
  __shared__ alignas(16) float rC[4];  // diff^2 partials
  __shared__ float vr[WIDTH];
  __shared__ float vc[WIDTH];

  const int tid = threadIdx.x;
  const int b = blockIdx.x;
  const int r0 = (tid >> 4) * 3;      // 16 row-groups of 3 rows
  const int c0 = (tid & 15) * 3;      // 16 col-groups of 3 cols
  const int ip = (r0 + 3) * PW + (c0 + 3);
  const int wid = tid >> 6;
  const int lane = tid & 63;

  // Zero halos (and interiors) of the padded grids.
  for (int i = tid; i < PH * PW; i += NT) { upad[i] = 0.f; vpad[i] = 0.f; }

  // Load this thread's 3x3 pixels of both images into registers.
  const float* xb = x + b * N;
  const float* yb = y + b * N;
  float xr[9], yr[9];
#pragma unroll
  for (int r = 0; r < 3; ++r)
#pragma unroll
    for (int k = 0; k < 3; ++k) {
      xr[r * 3 + k] = xb[(r0 + r) * WIDTH + c0 + k];
      yr[r * 3 + k] = yb[(r0 + r) * WIDTH + c0 + k];
    }
  {
    float sx = 0.f, sy = 0.f;
#pragma unroll
    for (int i = 0; i < 9; ++i) { sx += xr[i]; sy += yr[i]; }
    sx = wave_sum(sx); sy = wave_sum(sy);
    if (lane == 0) { rA[wid] = sx; rB[wid] = sy; }
  }
  __syncthreads();  // B0: publishes rA/rB partials + zeroed pads
  const float irx = __builtin_amdgcn_rcpf(sum4(rA));
  const float iry = __builtin_amdgcn_rcpf(sum4(rB));
#pragma unroll
  for (int i = 0; i < 9; ++i) { xr[i] *= irx; yr[i] *= iry; }

  float ur[9];
#pragma unroll
  for (int i = 0; i < 9; ++i) ur[i] = 1.0f / (float)N;
#pragma unroll
  for (int r = 0; r < 3; ++r)
#pragma unroll
    for (int k = 0; k < 3; ++k) upad[ip + r * PW + k] = ur[r * 3 + k];
  __syncthreads();  // B1: separates rA/rB reads above from rewrite below
  if (tid < NWAVE) { rA[tid] = 1.0f / (float)NWAVE; rC[tid] = 1.0f; }
  __syncthreads();  // B2: publishes rA (Su(u0)=1), rC dummy, upad interior

  float cc[9], vv[9];
  for (int iter = 0; iter < MAX_ITERS; ++iter) {
    // Partial sums published at the last barrier; independent of the conv, so
    // their read latency hides behind it.
    const float Su = sum4(rA);
    const float dsq = sum4(rC);
    conv_tile<0>(upad, ip, ur, cc);
    // Reference freezes u at the first iter (i>0) with diff<TOL; dsq here is
    // from iteration (iter-1). Break before any state write -> exact match.
    if (iter >= 2 && dsq < TOLSQ) break;
    const float base = EPS * Su;
    float pv = 0.f;
#pragma unroll
    for (int i = 0; i < 9; ++i) {
      vv[i] = yr[i] * __builtin_amdgcn_rcpf(base + cc[i]);
      pv += vv[i];
    }
#pragma unroll
    for (int r = 0; r < 3; ++r)
#pragma unroll
      for (int k = 0; k < 3; ++k) vpad[ip + r * PW + k] = vv[r * 3 + k];
    pv = wave_sum(pv);
    if (lane == 0) rB[wid] = pv;
    __syncthreads();  // A: publishes vpad + Sv partials

    const float Sv = sum4(rB);  // hides behind conv(vpad)
    conv_tile<0>(vpad, ip, vv, cc);
    const float base2 = EPS * Sv;
    float psu = 0.f, pd = 0.f;
#pragma unroll
    for (int i = 0; i < 9; ++i) {
      const float un = xr[i] * __builtin_amdgcn_rcpf(base2 + cc[i]);
      const float d = ur[i] - un;
      ur[i] = un;
      psu += un;
      pd += d * d;
    }
#pragma unroll
    for (int r = 0; r < 3; ++r)
#pragma unroll
      for (int k = 0; k < 3; ++k) upad[ip + r * PW + k] = ur[r * 3 + k];
    psu = wave_sum(psu);
    pd = wave_sum(pd);
    if (lane == 0) { rA[wid] = psu; rC[wid] = pd; }
    __syncthreads();  // B: publishes upad + Su/diff partials
  }

  // Final v from converged u. rA partials match current upad on both exit paths.
  const float SuF = sum4(rA);
  conv_tile<0>(upad, ip, ur, cc);
  const float base = EPS * SuF;
#pragma unroll
  for (int i = 0; i < 9; ++i) vv[i] = yr[i] * __builtin_amdgcn_rcpf(base + cc[i]);
#pragma unroll
  for (int r = 0; r < 3; ++r)
#pragma unroll
    for (int k = 0; k < 3; ++k) vpad[ip + r * PW + k] = vv[r * 3 + k];
  __syncthreads();

  // Row/col marginals of v for the separable eps*(C @ v) term (one-time).
  if (tid < WIDTH) {
    float s = 0.f;
    const float* rp = vpad + (tid + 3) * PW + 3;
    for (int c = 0; c < WIDTH; ++c) s += rp[c];
    vr[tid] = s;
  } else if (tid >= 64 && tid < 64 + WIDTH) {
    const int c = tid - 64;
    float s = 0.f;
    const float* cp = vpad + 3 * PW + 3 + c;
    for (int r = 0; r < WIDTH; ++r) s += cp[r * PW];
    vc[c] = s;
  }
  __syncthreads();

  // dist_b = sum_j u_j * ( eps*(Cv)_j + distance-weighted local conv )
  float aD[9];
  conv_tile<1>(vpad, ip, vv, aD);
  float part = 0.f;
#pragma unroll
  for (int r = 0; r < 3; ++r) {
    const int rr = r0 + r;
    float cvr = 0.f;
    for (int q = 0; q < WIDTH; ++q) cvr += vr[q] * fabsf((float)(q - rr));
#pragma unroll
    for (int k = 0; k < 3; ++k) {
      const int ccol = c0 + k;
      float cvc = 0.f;
      for (int q = 0; q < WIDTH; ++q) cvc += vc[q] * fabsf((float)(q - ccol));
      part += ur[r * 3 + k] * (EPS * (cvr + cvc) + aD[r * 3 + k]);
    }
  }
  {
    const float p = wave_sum(part);
    if (lane == 0) rA[wid] = p;  // WAR on rA separated by the two barriers above
  }
  __syncthreads();
  if (tid == 0) out[b] = sum4(rA);
}

extern "C" void kernel_launch(void* const* d_in, const int* in_sizes, int n_in,
                              void* d_out, int out_size, void* d_ws, size_t ws_size,
                              hipStream_t stream) {
  const float* x = (const float*)d_in[0];
  const float* y = (const float*)d_in[1];
  float* out = (float*)d_out;
  sinkhorn48<<<BATCH, NT, 0, stream>>>(x, y, out);
}